// Round 6
// baseline (146.048 us; speedup 1.0000x reference)
//
#include <hip/hip_runtime.h>
#include <math.h>

typedef _Float16 f16;
typedef __attribute__((ext_vector_type(8))) _Float16 f16x8;
typedef __attribute__((ext_vector_type(4))) _Float16 f16x4;
typedef __attribute__((ext_vector_type(4))) float f32x4;

constexpr int BATCH = 32;
constexpr int QL = 1024;
constexpr int KL = 1024;
constexpr int D = 128;
constexpr int BQ = 128;   // query rows per block: 4 waves x 32 rows
constexpr int BK = 64;    // key rows per tile
constexpr int DKP = 136;  // sK row pitch in halves (272 B)
constexpr int BKP = 72;   // sVT/sP row pitch in halves (144 B)

// scale * log2(e): softmax computed in exp2 domain
#define CSC 0.12752863187087177f

static __device__ __forceinline__ f16x4 pk4(float x, float y, float z, float w) {
  auto a = __builtin_amdgcn_cvt_pkrtz(x, y);   // __fp16 ext_vector(2)
  auto b = __builtin_amdgcn_cvt_pkrtz(z, w);
  f16x4 h;
  h[0] = (f16)a[0]; h[1] = (f16)a[1]; h[2] = (f16)b[0]; h[3] = (f16)b[1];
  return h;
}

__global__ __launch_bounds__(256, 1)
void attn_fwd(const float* __restrict__ Qp, const float* __restrict__ Kp,
              const float* __restrict__ Vp, const int* __restrict__ VLp,
              float* __restrict__ Op) {
  // double-buffered K/V tiles: ONE barrier per K-tile. 1 block/CU (90 KB LDS).
  __shared__ f16 sK[2][BK][DKP];   // ROW-PERMUTED: pos p holds key (p&15)*4+(p>>4)
  __shared__ f16 sVT[2][D][BKP];   // V tile transposed [d][kk], natural kk
  __shared__ f16 sP[4][32][BKP];   // per-wave P tile [row][kk]

  const int tid  = threadIdx.x;
  const int wave = tid >> 6, lane = tid & 63;
  const int l16  = lane & 15, quad = lane >> 4;

  // XCD-affinity swizzle: all 8 blocks of batch b share id%8 -> same XCD L2
  const int id = blockIdx.x;
  const int b  = (((id >> 3) & 3) << 3) | (id & 7);
  const int qt = id >> 5;                  // 0..7
  const int vl = VLp[b];

  const float* Kb = Kp + (size_t)b * KL * D;
  const float* Vb = Vp + (size_t)b * KL * D;
  const int ntiles = (vl + BK - 1) / BK;   // fully-masked tiles contribute exactly 0

  float4 kreg[8], vreg[8];

  // ---- prologue: load tile 0 into regs
  {
    const float4* Kt = (const float4*)Kb;
    #pragma unroll
    for (int i = 0; i < 8; ++i) kreg[i] = Kt[tid + i * 256];
    #pragma unroll
    for (int i = 0; i < 2; ++i) {
      int f = tid + i * 256;
      const float* base = Vb + (size_t)((f & 15) * 4) * D + (f >> 4) * 4;
      vreg[i * 4 + 0] = *(const float4*)(base);
      vreg[i * 4 + 1] = *(const float4*)(base + D);
      vreg[i * 4 + 2] = *(const float4*)(base + 2 * D);
      vreg[i * 4 + 3] = *(const float4*)(base + 3 * D);
    }
  }

  // ---- Q fragments: 2 row-groups (mt) x 4 k-chunks, registers for all tiles
  f16x8 qfrag[2][4];
  #pragma unroll
  for (int mt = 0; mt < 2; ++mt) {
    const float* Qb =
        Qp + ((size_t)(b * QL + qt * BQ + wave * 32 + mt * 16 + l16)) * D;
    #pragma unroll
    for (int kc = 0; kc < 4; ++kc) {
      const float* p = Qb + kc * 32 + quad * 8;
      float4 u = *(const float4*)p;
      float4 v = *(const float4*)(p + 4);
      f16x4 h0 = pk4(u.x, u.y, u.z, u.w);
      f16x4 h1 = pk4(v.x, v.y, v.z, v.w);
      f16x8 f;
      f[0] = h0[0]; f[1] = h0[1]; f[2] = h0[2]; f[3] = h0[3];
      f[4] = h1[0]; f[5] = h1[1]; f[6] = h1[2]; f[7] = h1[3];
      qfrag[mt][kc] = f;
    }
  }

  float m2[2][4], lsum[2][4];
  f32x4 o[2][8];
  #pragma unroll
  for (int mt = 0; mt < 2; ++mt)
    #pragma unroll
    for (int r = 0; r < 4; ++r) { m2[mt][r] = -INFINITY; lsum[mt][r] = 0.f; }
  #pragma unroll
  for (int mt = 0; mt < 2; ++mt)
    #pragma unroll
    for (int dt = 0; dt < 8; ++dt) o[mt][dt] = (f32x4){0.f, 0.f, 0.f, 0.f};

  // ---- drain tile 0 into buffer 0
  #pragma unroll
  for (int i = 0; i < 8; ++i) {
    int row = (tid + i * 256) >> 5;
    int rp = (row & 3) * 16 + (row >> 2);
    float4 u = kreg[i];
    *(f16x4*)&sK[0][rp][(tid & 31) * 4] = pk4(u.x, u.y, u.z, u.w);
  }
  #pragma unroll
  for (int i = 0; i < 2; ++i) {
    int f = tid + i * 256;
    int k0 = (f & 15) * 4, d0 = (f >> 4) * 4;
    float4 r0 = vreg[i*4+0], r1 = vreg[i*4+1], r2 = vreg[i*4+2], r3 = vreg[i*4+3];
    *(f16x4*)&sVT[0][d0 + 0][k0] = pk4(r0.x, r1.x, r2.x, r3.x);
    *(f16x4*)&sVT[0][d0 + 1][k0] = pk4(r0.y, r1.y, r2.y, r3.y);
    *(f16x4*)&sVT[0][d0 + 2][k0] = pk4(r0.z, r1.z, r2.z, r3.z);
    *(f16x4*)&sVT[0][d0 + 3][k0] = pk4(r0.w, r1.w, r2.w, r3.w);
  }
  __syncthreads();

  for (int t = 0; t < ntiles; ++t) {
    const int cur = t & 1, nxt = cur ^ 1;
    const bool more = (t + 1 < ntiles);

    // ---- issue global loads for tile t+1 (launch_bounds(256,1): 512-VGPR
    //      budget keeps all 16 float4 live -> loads stay hoisted here)
    if (more) {
      const float4* Kt = (const float4*)(Kb + (size_t)(t + 1) * BK * D);
      #pragma unroll
      for (int i = 0; i < 8; ++i) kreg[i] = Kt[tid + i * 256];
      const float* Vt = Vb + (size_t)(t + 1) * BK * D;
      #pragma unroll
      for (int i = 0; i < 2; ++i) {
        int f = tid + i * 256;
        const float* base = Vt + (size_t)((f & 15) * 4) * D + (f >> 4) * 4;
        vreg[i * 4 + 0] = *(const float4*)(base);
        vreg[i * 4 + 1] = *(const float4*)(base + D);
        vreg[i * 4 + 2] = *(const float4*)(base + 2 * D);
        vreg[i * 4 + 3] = *(const float4*)(base + 3 * D);
      }
    }

    // ---- S = Q K^T : 2 mt x 4 ct x 4 kc MFMA; kf reads shared across mt
    f32x4 s[2][4];
    #pragma unroll
    for (int ct = 0; ct < 4; ++ct) {
      f32x4 c0 = (f32x4){0.f, 0.f, 0.f, 0.f};
      f32x4 c1 = (f32x4){0.f, 0.f, 0.f, 0.f};
      #pragma unroll
      for (int kc = 0; kc < 4; ++kc) {
        f16x8 kf = *(const f16x8*)&sK[cur][ct * 16 + l16][kc * 32 + quad * 8];
        c0 = __builtin_amdgcn_mfma_f32_16x16x32_f16(qfrag[0][kc], kf, c0, 0, 0, 0);
        c1 = __builtin_amdgcn_mfma_f32_16x16x32_f16(qfrag[1][kc], kf, c1, 0, 0, 0);
      }
      s[0][ct] = c0;
      s[1][ct] = c1;
    }

    // ---- scale into log2 domain + key-padding mask (kk = t*64 + l16*4 + ct)
    #pragma unroll
    for (int ct = 0; ct < 4; ++ct) {
      bool ok = (t * BK + l16 * 4 + ct) < vl;
      #pragma unroll
      for (int mt = 0; mt < 2; ++mt)
        #pragma unroll
        for (int r = 0; r < 4; ++r)
          s[mt][ct][r] = ok ? s[mt][ct][r] * CSC : -1.0e9f;
    }

    // ---- online softmax per mt (16-lane group owns rows quad*4+r)
    #pragma unroll
    for (int mt = 0; mt < 2; ++mt) {
      float mnew[4], alpha[4], ls[4];
      #pragma unroll
      for (int r = 0; r < 4; ++r) {
        float v = fmaxf(fmaxf(s[mt][0][r], s[mt][1][r]),
                        fmaxf(s[mt][2][r], s[mt][3][r]));
        v = fmaxf(v, __shfl_xor(v, 1));
        v = fmaxf(v, __shfl_xor(v, 2));
        v = fmaxf(v, __shfl_xor(v, 4));
        v = fmaxf(v, __shfl_xor(v, 8));
        mnew[r]  = fmaxf(m2[mt][r], v);
        alpha[r] = __builtin_amdgcn_exp2f(m2[mt][r] - mnew[r]);
        m2[mt][r] = mnew[r];
        ls[r] = 0.f;
      }
      #pragma unroll
      for (int ct = 0; ct < 4; ++ct)
        #pragma unroll
        for (int r = 0; r < 4; ++r) {
          float p = __builtin_amdgcn_exp2f(s[mt][ct][r] - mnew[r]);
          s[mt][ct][r] = p;
          ls[r] += p;
        }
      #pragma unroll
      for (int r = 0; r < 4; ++r) {
        float v = ls[r];
        v += __shfl_xor(v, 1);
        v += __shfl_xor(v, 2);
        v += __shfl_xor(v, 4);
        v += __shfl_xor(v, 8);
        lsum[mt][r] = lsum[mt][r] * alpha[r] + v;
        // P -> LDS: 4 ct-values are kk-contiguous (l16*4+ct) -> ds_write_b64
        *(f16x4*)&sP[wave][mt * 16 + quad * 4 + r][l16 * 4] =
            pk4(s[mt][0][r], s[mt][1][r], s[mt][2][r], s[mt][3][r]);
        // rescale O
        #pragma unroll
        for (int dt = 0; dt < 8; ++dt) o[mt][dt][r] *= alpha[r];
      }
    }

    // sP is wave-private: in-wave DS ordering + waitcnt suffices (no barrier)
    asm volatile("s_waitcnt lgkmcnt(0)" ::: "memory");

    // ---- O += P V : vf reads shared across mt
    #pragma unroll
    for (int ks = 0; ks < 2; ++ks) {
      f16x8 pf0 = *(const f16x8*)&sP[wave][l16][ks * 32 + quad * 8];
      f16x8 pf1 = *(const f16x8*)&sP[wave][16 + l16][ks * 32 + quad * 8];
      #pragma unroll
      for (int dt = 0; dt < 8; ++dt) {
        f16x8 vf = *(const f16x8*)&sVT[cur][dt * 16 + l16][ks * 32 + quad * 8];
        o[0][dt] = __builtin_amdgcn_mfma_f32_16x16x32_f16(pf0, vf, o[0][dt], 0, 0, 0);
        o[1][dt] = __builtin_amdgcn_mfma_f32_16x16x32_f16(pf1, vf, o[1][dt], 0, 0, 0);
      }
    }

    // ---- drain prefetch regs into the other buffer
    if (more) {
      #pragma unroll
      for (int i = 0; i < 8; ++i) {
        int row = (tid + i * 256) >> 5;
        int rp = (row & 3) * 16 + (row >> 2);
        float4 u = kreg[i];
        *(f16x4*)&sK[nxt][rp][(tid & 31) * 4] = pk4(u.x, u.y, u.z, u.w);
      }
      #pragma unroll
      for (int i = 0; i < 2; ++i) {
        int f = tid + i * 256;
        int k0 = (f & 15) * 4, d0 = (f >> 4) * 4;
        float4 r0 = vreg[i*4+0], r1 = vreg[i*4+1], r2 = vreg[i*4+2], r3 = vreg[i*4+3];
        *(f16x4*)&sVT[nxt][d0 + 0][k0] = pk4(r0.x, r1.x, r2.x, r3.x);
        *(f16x4*)&sVT[nxt][d0 + 1][k0] = pk4(r0.y, r1.y, r2.y, r3.y);
        *(f16x4*)&sVT[nxt][d0 + 2][k0] = pk4(r0.z, r1.z, r2.z, r3.z);
        *(f16x4*)&sVT[nxt][d0 + 3][k0] = pk4(r0.w, r1.w, r2.w, r3.w);
      }
    }
    __syncthreads();
  }

  // ---- epilogue: O /= l, C-layout store (64B segments per 16 lanes)
  float* Ob = Op + ((size_t)(b * QL + qt * BQ + wave * 32)) * D;
  #pragma unroll
  for (int mt = 0; mt < 2; ++mt)
    #pragma unroll
    for (int r = 0; r < 4; ++r) {
      float inv = 1.0f / lsum[mt][r];
      int row = mt * 16 + quad * 4 + r;
      #pragma unroll
      for (int dt = 0; dt < 8; ++dt)
        Ob[(size_t)row * D + dt * 16 + l16] = o[mt][dt][r] * inv;
    }
}

extern "C" void kernel_launch(void* const* d_in, const int* in_sizes, int n_in,
                              void* d_out, int out_size, void* d_ws, size_t ws_size,
                              hipStream_t stream) {
  const float* Qp = (const float*)d_in[0];
  const float* Kp = (const float*)d_in[1];
  const float* Vp = (const float*)d_in[2];
  const int*   VL = (const int*)d_in[3];
  float* Op = (float*)d_out;

  attn_fwd<<<dim3(QL / BQ * BATCH), dim3(256), 0, stream>>>(Qp, Kp, Vp, VL, Op);
}